// Round 3
// baseline (1629.230 us; speedup 1.0000x reference)
//
#include <hip/hip_runtime.h>

#define NN 50000
#define NE 800000
#define IN_CH 128
#define HID 256
#define NG 1024
#define BN_EPS 1e-5f

// ================= CSR build =================
__global__ void hist_dst(const int* __restrict__ dst, int* __restrict__ cnt) {
    int e = blockIdx.x * blockDim.x + threadIdx.x;
    if (e < NE) atomicAdd(&cnt[dst[e]], 1);
}

// per-block sums of cnt (196 blocks x 256)
__global__ void scan_bsum(const int* __restrict__ cnt, int* __restrict__ bsum) {
    __shared__ int red[256];
    int t = threadIdx.x;
    int i = blockIdx.x * 256 + t;
    red[t] = (i < NN) ? cnt[i] : 0;
    __syncthreads();
    for (int s = 128; s > 0; s >>= 1) {
        if (t < s) red[t] += red[t + s];
        __syncthreads();
    }
    if (t == 0) bsum[blockIdx.x] = red[0];
}

// single block: exclusive scan of 196 block sums
__global__ void scan_offsets(const int* __restrict__ bsum, int* __restrict__ bofs,
                             int* __restrict__ row_ptr) {
    __shared__ int sh[256];
    int t = threadIdx.x;
    sh[t] = (t < 196) ? bsum[t] : 0;
    __syncthreads();
    for (int off = 1; off < 256; off <<= 1) {
        int v = (t >= off) ? sh[t - off] : 0;
        __syncthreads();
        sh[t] += v;
        __syncthreads();
    }
    if (t < 196) bofs[t] = (t == 0) ? 0 : sh[t - 1];
    if (t == 0) row_ptr[NN] = NE;
}

// per-block exclusive scan + emit row_ptr/cursor/dinv
__global__ void scan_emit(const int* __restrict__ cnt, const int* __restrict__ bofs,
                          int* __restrict__ row_ptr, int* __restrict__ cursor,
                          float* __restrict__ dinv) {
    __shared__ int sh[256];
    int t = threadIdx.x;
    int i = blockIdx.x * 256 + t;
    int ci = (i < NN) ? cnt[i] : 0;
    sh[t] = ci;
    __syncthreads();
    for (int off = 1; off < 256; off <<= 1) {
        int v = (t >= off) ? sh[t - off] : 0;
        __syncthreads();
        sh[t] += v;
        __syncthreads();
    }
    if (i < NN) {
        int run = bofs[blockIdx.x] + sh[t] - ci;   // exclusive
        row_ptr[i] = run;
        cursor[i] = run;
        dinv[i] = rsqrtf(1.0f + (float)ci);
    }
}

__global__ void csr_fill(const int* __restrict__ src, const int* __restrict__ dst,
                         const float* __restrict__ dinv, int* __restrict__ cursor,
                         int* __restrict__ src_sorted, float* __restrict__ w_sorted) {
    int e = blockIdx.x * blockDim.x + threadIdx.x;
    if (e >= NE) return;
    int s = src[e], d = dst[e];
    int pos = atomicAdd(&cursor[d], 1);
    src_sorted[pos] = s;
    w_sorted[pos] = dinv[s] * dinv[d];
}

// ================= GEMM with optional fused BN-affine+ReLU on A =================
// C[M,256] = f(A)[M,K] @ W[K,256] + bias, f(a)_k = relu(a*scale[k]+shift[k]) or identity
template <int K>
__global__ void gemm_bias_n256(const float* __restrict__ A,
                               const float* __restrict__ W,
                               const float* __restrict__ bias,
                               const float* __restrict__ a_scale,
                               const float* __restrict__ a_shift,
                               float* __restrict__ C, int M) {
    __shared__ float As[32][32];
    const int tid  = threadIdx.x;
    const int lane = tid & 63;
    const int wv   = tid >> 6;
    const int c0   = lane * 4;
    const int r0   = wv * 8;
    const int m0   = blockIdx.x * 32;

    float acc[8][4];
#pragma unroll
    for (int m = 0; m < 8; m++)
#pragma unroll
        for (int j = 0; j < 4; j++) acc[m][j] = 0.f;

    for (int kc = 0; kc < K; kc += 32) {
        __syncthreads();
#pragma unroll
        for (int i = 0; i < 4; i++) {
            int elem = tid + i * 256;
            int r = elem >> 5, kk = elem & 31;
            int row = m0 + r;
            float a = (row < M) ? A[row * K + kc + kk] : 0.f;
            if (a_scale) a = fmaxf(a * a_scale[kc + kk] + a_shift[kc + kk], 0.f);
            As[r][kk] = a;
        }
        __syncthreads();
#pragma unroll
        for (int kk = 0; kk < 32; kk++) {
            const float4 w4 = *(const float4*)&W[(kc + kk) * 256 + c0];
#pragma unroll
            for (int m = 0; m < 8; m++) {
                float a = As[r0 + m][kk];
                acc[m][0] += a * w4.x;
                acc[m][1] += a * w4.y;
                acc[m][2] += a * w4.z;
                acc[m][3] += a * w4.w;
            }
        }
    }

    float4 bb = make_float4(0.f, 0.f, 0.f, 0.f);
    if (bias) bb = *(const float4*)&bias[c0];
#pragma unroll
    for (int m = 0; m < 8; m++) {
        int row = m0 + r0 + m;
        if (row < M) {
            float4 o;
            o.x = acc[m][0] + bb.x;
            o.y = acc[m][1] + bb.y;
            o.z = acc[m][2] + bb.z;
            o.w = acc[m][3] + bb.w;
            *(float4*)&C[row * 256 + c0] = o;
        }
    }
}

// ================= aggregation with fused BN-stats =================
// outh[d,:] = hw[d,:]/(1+deg_d) + bias + sum_e hw[src[e],:]*w[e]
// epilogue: per-block column sums of out and out^2 -> atomicAdd into ssum/ssq
__global__ void gcn_aggregate(const float* __restrict__ hw,
                              const int* __restrict__ row_ptr,
                              const int* __restrict__ src_sorted,
                              const float* __restrict__ w_sorted,
                              const float* __restrict__ bias,
                              float* __restrict__ outh,
                              float* __restrict__ ssum, float* __restrict__ ssq) {
    const int wv   = threadIdx.x >> 6;
    const int lane = threadIdx.x & 63;
    const int d    = blockIdx.x * 4 + wv;     // NN % 4 == 0
    const int c0   = lane * 4;

    const int e0 = row_ptr[d];
    const int e1 = row_ptr[d + 1];
    const float sl = 1.0f / (1.0f + (float)(e1 - e0));   // dinv[d]^2

    float4 b = *(const float4*)&bias[c0];
    float4 v = *(const float4*)&hw[d * HID + c0];
    float4 acc;
    acc.x = v.x * sl + b.x;
    acc.y = v.y * sl + b.y;
    acc.z = v.z * sl + b.z;
    acc.w = v.w * sl + b.w;

    int e = e0;
    for (; e + 4 <= e1; e += 4) {
        int   s0 = src_sorted[e],     s1 = src_sorted[e + 1];
        int   s2 = src_sorted[e + 2], s3 = src_sorted[e + 3];
        float w0 = w_sorted[e],       w1 = w_sorted[e + 1];
        float w2 = w_sorted[e + 2],   w3 = w_sorted[e + 3];
        float4 a0 = *(const float4*)&hw[s0 * HID + c0];
        float4 a1 = *(const float4*)&hw[s1 * HID + c0];
        float4 a2 = *(const float4*)&hw[s2 * HID + c0];
        float4 a3 = *(const float4*)&hw[s3 * HID + c0];
        acc.x += a0.x * w0 + a1.x * w1 + a2.x * w2 + a3.x * w3;
        acc.y += a0.y * w0 + a1.y * w1 + a2.y * w2 + a3.y * w3;
        acc.z += a0.z * w0 + a1.z * w1 + a2.z * w2 + a3.z * w3;
        acc.w += a0.w * w0 + a1.w * w1 + a2.w * w2 + a3.w * w3;
    }
    for (; e < e1; e++) {
        int   s0 = src_sorted[e];
        float w0 = w_sorted[e];
        float4 a0 = *(const float4*)&hw[s0 * HID + c0];
        acc.x += a0.x * w0;
        acc.y += a0.y * w0;
        acc.z += a0.z * w0;
        acc.w += a0.w * w0;
    }
    *(float4*)&outh[d * HID + c0] = acc;

    // fused BN stats
    __shared__ float ls[4][256];
    __shared__ float lq[4][256];
    *(float4*)&ls[wv][c0] = acc;
    float4 q;
    q.x = acc.x * acc.x; q.y = acc.y * acc.y;
    q.z = acc.z * acc.z; q.w = acc.w * acc.w;
    *(float4*)&lq[wv][c0] = q;
    __syncthreads();
    int c = threadIdx.x;   // channel 0..255
    float s = ls[0][c] + ls[1][c] + ls[2][c] + ls[3][c];
    float qq = lq[0][c] + lq[1][c] + lq[2][c] + lq[3][c];
    atomicAdd(&ssum[c], s);
    atomicAdd(&ssq[c], qq);
}

// ================= batchnorm =================
__global__ void bn_stats(const float* __restrict__ h, float* __restrict__ sum,
                         float* __restrict__ sumsq, int M) {
    int c = threadIdx.x;
    float s = 0.f, q = 0.f;
    for (int r = blockIdx.x; r < M; r += gridDim.x) {
        float v = h[r * HID + c];
        s += v;
        q += v * v;
    }
    atomicAdd(&sum[c], s);
    atomicAdd(&sumsq[c], q);
}

__global__ void bn_finalize(const float* __restrict__ sum,
                            const float* __restrict__ sumsq,
                            const float* __restrict__ gamma,
                            const float* __restrict__ beta,
                            float* __restrict__ scale, float* __restrict__ shift,
                            float invM) {
    int c = threadIdx.x;
    float mu = sum[c] * invM;
    float var = sumsq[c] * invM - mu * mu;
    float inv = rsqrtf(var + BN_EPS);
    float sc = inv * gamma[c];
    scale[c] = sc;
    shift[c] = beta[c] - mu * sc;
}

// ================= pooling (fused BN3 affine+relu, segmented atomics) =================
__global__ void pool_sum(const float* __restrict__ h, const int* __restrict__ batch,
                         const float* __restrict__ scale, const float* __restrict__ shift,
                         float* __restrict__ pooled) {
    int c = threadIdx.x;
    int i0 = blockIdx.x * 64;
    int i1 = (i0 + 64 < NN) ? i0 + 64 : NN;
    float sc = scale[c], sh = shift[c];
    float acc = 0.f;
    int g = batch[i0];
    for (int i = i0; i < i1; i++) {
        int gi = batch[i];
        if (gi != g) {
            atomicAdd(&pooled[g * HID + c], acc);
            acc = 0.f;
            g = gi;
        }
        acc += fmaxf(h[i * HID + c] * sc + sh, 0.f);
    }
    atomicAdd(&pooled[g * HID + c], acc);
}

__global__ void graph_counts(const int* __restrict__ batch, float* __restrict__ counts) {
    int g = blockIdx.x * blockDim.x + threadIdx.x;
    if (g >= NG) return;
    // upper_bound(g) - upper_bound(g-1) on sorted batch
    int lo = 0, hi = NN;
    while (lo < hi) { int m = (lo + hi) >> 1; if (batch[m] <= g) lo = m + 1; else hi = m; }
    int ub1 = lo;
    lo = 0; hi = NN;
    int gm = g - 1;
    while (lo < hi) { int m = (lo + hi) >> 1; if (batch[m] <= gm) lo = m + 1; else hi = m; }
    counts[g] = (float)(ub1 - lo);
}

__global__ void pool_div(float* __restrict__ pooled, const float* __restrict__ counts) {
    int idx = blockIdx.x * blockDim.x + threadIdx.x;
    if (idx >= NG * HID) return;
    int g = idx >> 8;
    pooled[idx] /= fmaxf(counts[g], 1.0f);
}

// ================= head =================
__global__ void final_out(const float* __restrict__ z, const float* __restrict__ scale,
                          const float* __restrict__ shift, const float* __restrict__ W2,
                          const float* __restrict__ b2, float* __restrict__ out) {
    int g = blockIdx.x;
    int c = threadIdx.x;
    float v = z[g * HID + c] * scale[c] + shift[c];
    v = fmaxf(v, 0.f) * W2[c];
    __shared__ float red[256];
    red[c] = v;
    __syncthreads();
    for (int s = 128; s > 0; s >>= 1) {
        if (c < s) red[c] += red[c + s];
        __syncthreads();
    }
    if (c == 0) out[g] = red[0] + b2[0];
}

// ================= launch =================
extern "C" void kernel_launch(void* const* d_in, const int* in_sizes, int n_in,
                              void* d_out, int out_size, void* d_ws, size_t ws_size,
                              hipStream_t stream) {
    const float* x      = (const float*)d_in[0];
    const int*   ei     = (const int*)d_in[1];
    const int*   batch  = (const int*)d_in[2];
    const float* W_emb  = (const float*)d_in[3];
    const float* b_emb  = (const float*)d_in[4];
    const float* W_conv = (const float*)d_in[5];
    const float* b_conv = (const float*)d_in[6];
    const float* gamma  = (const float*)d_in[7];
    const float* beta   = (const float*)d_in[8];
    const float* W1     = (const float*)d_in[9];
    const float* b1     = (const float*)d_in[10];
    const float* g2     = (const float*)d_in[11];
    const float* bt2    = (const float*)d_in[12];
    const float* W2     = (const float*)d_in[13];
    const float* b2     = (const float*)d_in[14];
    float* out = (float*)d_out;

    const int* src = ei;
    const int* dst = ei + NE;

    float* ws = (float*)d_ws;
    float* h          = ws;                          // NN*HID
    float* hw         = h + (size_t)NN * HID;        // NN*HID
    float* dinv       = hw + (size_t)NN * HID;       // NN
    float* stats      = dinv + NN;                   // 1024
    int*   cnt        = (int*)(stats + 1024);        // NN
    int*   row_ptr    = cnt + NN;                    // NN+1
    int*   cursor     = row_ptr + NN + 1;            // NN
    int*   bsum       = cursor + NN;                 // 256
    int*   bofs       = bsum + 256;                  // 256
    int*   src_sorted = bofs + 256;                  // NE
    float* w_sorted   = (float*)(src_sorted + NE);   // NE
    float* pooled = (float*)(src_sorted);            // aliases CSR (dead by pool time)
    float* counts = w_sorted;                        // aliases
    float* ssum  = stats;
    float* ssq   = stats + 256;
    float* scale = stats + 512;
    float* shift = stats + 768;
    float* z     = hw;

    const int B = 256;
    const int SB = (NN + 255) / 256;   // 196

    // ---- CSR build ----
    hipMemsetAsync(cnt, 0, NN * sizeof(int), stream);
    hist_dst<<<(NE + B - 1) / B, B, 0, stream>>>(dst, cnt);
    scan_bsum<<<SB, B, 0, stream>>>(cnt, bsum);
    scan_offsets<<<1, B, 0, stream>>>(bsum, bofs, row_ptr);
    scan_emit<<<SB, B, 0, stream>>>(cnt, bofs, row_ptr, cursor, dinv);
    csr_fill<<<(NE + B - 1) / B, B, 0, stream>>>(src, dst, dinv, cursor,
                                                 src_sorted, w_sorted);

    // ---- embedding ----
    gemm_bias_n256<IN_CH><<<(NN + 31) / 32, B, 0, stream>>>(
        x, W_emb, b_emb, nullptr, nullptr, h, NN);

    // ---- conv layers (BN affine fused into next consumer) ----
    for (int l = 0; l < 3; l++) {
        const float* Wl = W_conv + (size_t)l * HID * HID;
        const float* bl = b_conv + (size_t)l * HID;
        // hw = f(h) @ Wl ; f = BN_{l-1} affine + relu (identity for l==0)
        gemm_bias_n256<HID><<<(NN + 31) / 32, B, 0, stream>>>(
            h, Wl, nullptr,
            (l == 0) ? nullptr : scale, (l == 0) ? nullptr : shift, hw, NN);
        hipMemsetAsync(stats, 0, 512 * sizeof(float), stream);   // ssum/ssq
        gcn_aggregate<<<NN / 4, B, 0, stream>>>(hw, row_ptr, src_sorted, w_sorted,
                                                bl, h, ssum, ssq);
        bn_finalize<<<1, B, 0, stream>>>(ssum, ssq, gamma + l * HID, beta + l * HID,
                                         scale, shift, 1.0f / NN);
    }

    // ---- pool (BN3 affine + relu fused) ----
    hipMemsetAsync(pooled, 0, (size_t)NG * HID * sizeof(float), stream);
    pool_sum<<<(NN + 63) / 64, B, 0, stream>>>(h, batch, scale, shift, pooled);
    graph_counts<<<(NG + B - 1) / B, B, 0, stream>>>(batch, counts);
    pool_div<<<(NG * HID + B - 1) / B, B, 0, stream>>>(pooled, counts);

    // ---- readout ----
    gemm_bias_n256<HID><<<(NG + 31) / 32, B, 0, stream>>>(
        pooled, W1, b1, nullptr, nullptr, z, NG);
    hipMemsetAsync(stats, 0, 512 * sizeof(float), stream);
    bn_stats<<<64, B, 0, stream>>>(z, ssum, ssq, NG);
    bn_finalize<<<1, B, 0, stream>>>(ssum, ssq, g2, bt2, scale, shift, 1.0f / NG);
    final_out<<<NG, B, 0, stream>>>(z, scale, shift, W2, b2, out);
}

// Round 4
// 838.908 us; speedup vs baseline: 1.9421x; 1.9421x over previous
//
#include <hip/hip_runtime.h>
#include <hip/hip_fp16.h>

#define NN 50000
#define NE 800000
#define IN_CH 128
#define HID 256
#define NG 1024
#define BN_EPS 1e-5f
#define NPART 64   // BN-stats partial buffers

static __device__ inline unsigned short f2h(float f) {
    __half h = __float2half(f);                 // RNE
    return reinterpret_cast<__half_raw*>(&h)->x;
}
static __device__ inline float h2f(unsigned short u) {
    __half_raw r; r.x = u;
    return __half2float(__half(r));
}

// ================= CSR build =================
__global__ void hist_dst(const int* __restrict__ dst, int* __restrict__ cnt) {
    int e = blockIdx.x * blockDim.x + threadIdx.x;
    if (e < NE) atomicAdd(&cnt[dst[e]], 1);
}

__global__ void scan_bsum(const int* __restrict__ cnt, int* __restrict__ bsum) {
    __shared__ int red[256];
    int t = threadIdx.x;
    int i = blockIdx.x * 256 + t;
    red[t] = (i < NN) ? cnt[i] : 0;
    __syncthreads();
    for (int s = 128; s > 0; s >>= 1) {
        if (t < s) red[t] += red[t + s];
        __syncthreads();
    }
    if (t == 0) bsum[blockIdx.x] = red[0];
}

__global__ void scan_offsets(const int* __restrict__ bsum, int* __restrict__ bofs,
                             int* __restrict__ row_ptr) {
    __shared__ int sh[256];
    int t = threadIdx.x;
    sh[t] = (t < 196) ? bsum[t] : 0;
    __syncthreads();
    for (int off = 1; off < 256; off <<= 1) {
        int v = (t >= off) ? sh[t - off] : 0;
        __syncthreads();
        sh[t] += v;
        __syncthreads();
    }
    if (t < 196) bofs[t] = (t == 0) ? 0 : sh[t - 1];
    if (t == 0) row_ptr[NN] = NE;
}

__global__ void scan_emit(const int* __restrict__ cnt, const int* __restrict__ bofs,
                          int* __restrict__ row_ptr, int* __restrict__ cursor,
                          float* __restrict__ dinv) {
    __shared__ int sh[256];
    int t = threadIdx.x;
    int i = blockIdx.x * 256 + t;
    int ci = (i < NN) ? cnt[i] : 0;
    sh[t] = ci;
    __syncthreads();
    for (int off = 1; off < 256; off <<= 1) {
        int v = (t >= off) ? sh[t - off] : 0;
        __syncthreads();
        sh[t] += v;
        __syncthreads();
    }
    if (i < NN) {
        int run = bofs[blockIdx.x] + sh[t] - ci;
        row_ptr[i] = run;
        cursor[i] = run;
        dinv[i] = rsqrtf(1.0f + (float)ci);
    }
}

__global__ void csr_fill(const int* __restrict__ src, const int* __restrict__ dst,
                         const float* __restrict__ dinv, int* __restrict__ cursor,
                         int* __restrict__ src_sorted, float* __restrict__ w_sorted) {
    int e = blockIdx.x * blockDim.x + threadIdx.x;
    if (e >= NE) return;
    int s = src[e], d = dst[e];
    int pos = atomicAdd(&cursor[d], 1);
    src_sorted[pos] = s;
    w_sorted[pos] = dinv[s] * dinv[d];
}

// ================= GEMM =================
// C[M,256] = f(A)[M,K] @ W[K,256] + bias; f = relu(a*scale+shift) if a_scale
// HOUT: write fp16 (packed ushort4) else fp32
template <int K, bool HOUT>
__global__ void gemm_bias_n256(const float* __restrict__ A,
                               const float* __restrict__ W,
                               const float* __restrict__ bias,
                               const float* __restrict__ a_scale,
                               const float* __restrict__ a_shift,
                               float* __restrict__ Cf,
                               ushort4* __restrict__ Ch, int M) {
    __shared__ float As[32][32];
    const int tid  = threadIdx.x;
    const int lane = tid & 63;
    const int wv   = tid >> 6;
    const int c0   = lane * 4;
    const int r0   = wv * 8;
    const int m0   = blockIdx.x * 32;

    float acc[8][4];
#pragma unroll
    for (int m = 0; m < 8; m++)
#pragma unroll
        for (int j = 0; j < 4; j++) acc[m][j] = 0.f;

    for (int kc = 0; kc < K; kc += 32) {
        __syncthreads();
#pragma unroll
        for (int i = 0; i < 4; i++) {
            int elem = tid + i * 256;
            int r = elem >> 5, kk = elem & 31;
            int row = m0 + r;
            float a = (row < M) ? A[row * K + kc + kk] : 0.f;
            if (a_scale) a = fmaxf(a * a_scale[kc + kk] + a_shift[kc + kk], 0.f);
            As[r][kk] = a;
        }
        __syncthreads();
#pragma unroll
        for (int kk = 0; kk < 32; kk++) {
            const float4 w4 = *(const float4*)&W[(kc + kk) * 256 + c0];
#pragma unroll
            for (int m = 0; m < 8; m++) {
                float a = As[r0 + m][kk];
                acc[m][0] += a * w4.x;
                acc[m][1] += a * w4.y;
                acc[m][2] += a * w4.z;
                acc[m][3] += a * w4.w;
            }
        }
    }

    float4 bb = make_float4(0.f, 0.f, 0.f, 0.f);
    if (bias) bb = *(const float4*)&bias[c0];
#pragma unroll
    for (int m = 0; m < 8; m++) {
        int row = m0 + r0 + m;
        if (row < M) {
            float ox = acc[m][0] + bb.x;
            float oy = acc[m][1] + bb.y;
            float oz = acc[m][2] + bb.z;
            float ow = acc[m][3] + bb.w;
            if (HOUT) {
                ushort4 p;
                p.x = f2h(ox); p.y = f2h(oy); p.z = f2h(oz); p.w = f2h(ow);
                Ch[row * 64 + lane] = p;
            } else {
                *(float4*)&Cf[row * 256 + c0] = make_float4(ox, oy, oz, ow);
            }
        }
    }
}

// ================= aggregation (fp16 gathers, fused BN-stats to partials) ====
__global__ void gcn_aggregate(const ushort4* __restrict__ hwh,
                              const int* __restrict__ row_ptr,
                              const int* __restrict__ src_sorted,
                              const float* __restrict__ w_sorted,
                              const float* __restrict__ bias,
                              float* __restrict__ outh,
                              float* __restrict__ bpart) {
    const int wv   = threadIdx.x >> 6;
    const int lane = threadIdx.x & 63;
    const int d    = blockIdx.x * 4 + wv;     // NN % 4 == 0
    const int c0   = lane * 4;

    const int e0 = row_ptr[d];
    const int e1 = row_ptr[d + 1];
    const float sl = 1.0f / (1.0f + (float)(e1 - e0));   // dinv[d]^2

    float4 b = *(const float4*)&bias[c0];
    ushort4 vr = hwh[d * 64 + lane];
    float4 acc;
    acc.x = h2f(vr.x) * sl + b.x;
    acc.y = h2f(vr.y) * sl + b.y;
    acc.z = h2f(vr.z) * sl + b.z;
    acc.w = h2f(vr.w) * sl + b.w;

    int e = e0;
    for (; e + 4 <= e1; e += 4) {
        int   s0 = src_sorted[e],     s1 = src_sorted[e + 1];
        int   s2 = src_sorted[e + 2], s3 = src_sorted[e + 3];
        float w0 = w_sorted[e],       w1 = w_sorted[e + 1];
        float w2 = w_sorted[e + 2],   w3 = w_sorted[e + 3];
        ushort4 a0 = hwh[s0 * 64 + lane];
        ushort4 a1 = hwh[s1 * 64 + lane];
        ushort4 a2 = hwh[s2 * 64 + lane];
        ushort4 a3 = hwh[s3 * 64 + lane];
        acc.x += h2f(a0.x) * w0 + h2f(a1.x) * w1 + h2f(a2.x) * w2 + h2f(a3.x) * w3;
        acc.y += h2f(a0.y) * w0 + h2f(a1.y) * w1 + h2f(a2.y) * w2 + h2f(a3.y) * w3;
        acc.z += h2f(a0.z) * w0 + h2f(a1.z) * w1 + h2f(a2.z) * w2 + h2f(a3.z) * w3;
        acc.w += h2f(a0.w) * w0 + h2f(a1.w) * w1 + h2f(a2.w) * w2 + h2f(a3.w) * w3;
    }
    for (; e < e1; e++) {
        int   s0 = src_sorted[e];
        float w0 = w_sorted[e];
        ushort4 a0 = hwh[s0 * 64 + lane];
        acc.x += h2f(a0.x) * w0;
        acc.y += h2f(a0.y) * w0;
        acc.z += h2f(a0.z) * w0;
        acc.w += h2f(a0.w) * w0;
    }
    *(float4*)&outh[d * HID + c0] = acc;

    // fused BN stats -> 64-way partials (kills same-address atomic serialization)
    __shared__ float ls[4][256];
    __shared__ float lq[4][256];
    *(float4*)&ls[wv][c0] = acc;
    float4 q;
    q.x = acc.x * acc.x; q.y = acc.y * acc.y;
    q.z = acc.z * acc.z; q.w = acc.w * acc.w;
    *(float4*)&lq[wv][c0] = q;
    __syncthreads();
    int c = threadIdx.x;
    float s  = ls[0][c] + ls[1][c] + ls[2][c] + ls[3][c];
    float qq = lq[0][c] + lq[1][c] + lq[2][c] + lq[3][c];
    float* pb = bpart + (blockIdx.x & (NPART - 1)) * 512;
    atomicAdd(&pb[c], s);
    atomicAdd(&pb[256 + c], qq);
}

// reduce partials -> scale/shift
__global__ void bn_finalize_part(const float* __restrict__ bpart,
                                 const float* __restrict__ gamma,
                                 const float* __restrict__ beta,
                                 float* __restrict__ scale, float* __restrict__ shift,
                                 float invM) {
    int c = threadIdx.x;
    float s = 0.f, q = 0.f;
    for (int p = 0; p < NPART; p++) {
        s += bpart[p * 512 + c];
        q += bpart[p * 512 + 256 + c];
    }
    float mu = s * invM;
    float var = q * invM - mu * mu;
    float inv = rsqrtf(var + BN_EPS);
    float sc = inv * gamma[c];
    scale[c] = sc;
    shift[c] = beta[c] - mu * sc;
}

// ================= readout BN =================
__global__ void bn_stats(const float* __restrict__ h, float* __restrict__ sum,
                         float* __restrict__ sumsq, int M) {
    int c = threadIdx.x;
    float s = 0.f, q = 0.f;
    for (int r = blockIdx.x; r < M; r += gridDim.x) {
        float v = h[r * HID + c];
        s += v;
        q += v * v;
    }
    atomicAdd(&sum[c], s);
    atomicAdd(&sumsq[c], q);
}

__global__ void bn_finalize(const float* __restrict__ sum,
                            const float* __restrict__ sumsq,
                            const float* __restrict__ gamma,
                            const float* __restrict__ beta,
                            float* __restrict__ scale, float* __restrict__ shift,
                            float invM) {
    int c = threadIdx.x;
    float mu = sum[c] * invM;
    float var = sumsq[c] * invM - mu * mu;
    float inv = rsqrtf(var + BN_EPS);
    float sc = inv * gamma[c];
    scale[c] = sc;
    shift[c] = beta[c] - mu * sc;
}

// ================= pooling =================
__global__ void pool_sum(const float* __restrict__ h, const int* __restrict__ batch,
                         const float* __restrict__ scale, const float* __restrict__ shift,
                         float* __restrict__ pooled) {
    int c = threadIdx.x;
    int i0 = blockIdx.x * 64;
    int i1 = (i0 + 64 < NN) ? i0 + 64 : NN;
    float sc = scale[c], sh = shift[c];
    float acc = 0.f;
    int g = batch[i0];
    for (int i = i0; i < i1; i++) {
        int gi = batch[i];
        if (gi != g) {
            atomicAdd(&pooled[g * HID + c], acc);
            acc = 0.f;
            g = gi;
        }
        acc += fmaxf(h[i * HID + c] * sc + sh, 0.f);
    }
    atomicAdd(&pooled[g * HID + c], acc);
}

__global__ void graph_counts(const int* __restrict__ batch, float* __restrict__ counts) {
    int g = blockIdx.x * blockDim.x + threadIdx.x;
    if (g >= NG) return;
    int lo = 0, hi = NN;
    while (lo < hi) { int m = (lo + hi) >> 1; if (batch[m] <= g) lo = m + 1; else hi = m; }
    int ub1 = lo;
    lo = 0; hi = NN;
    int gm = g - 1;
    while (lo < hi) { int m = (lo + hi) >> 1; if (batch[m] <= gm) lo = m + 1; else hi = m; }
    counts[g] = (float)(ub1 - lo);
}

__global__ void pool_div(float* __restrict__ pooled, const float* __restrict__ counts) {
    int idx = blockIdx.x * blockDim.x + threadIdx.x;
    if (idx >= NG * HID) return;
    int g = idx >> 8;
    pooled[idx] /= fmaxf(counts[g], 1.0f);
}

// ================= head =================
__global__ void final_out(const float* __restrict__ z, const float* __restrict__ scale,
                          const float* __restrict__ shift, const float* __restrict__ W2,
                          const float* __restrict__ b2, float* __restrict__ out) {
    int g = blockIdx.x;
    int c = threadIdx.x;
    float v = z[g * HID + c] * scale[c] + shift[c];
    v = fmaxf(v, 0.f) * W2[c];
    __shared__ float red[256];
    red[c] = v;
    __syncthreads();
    for (int s = 128; s > 0; s >>= 1) {
        if (c < s) red[c] += red[c + s];
        __syncthreads();
    }
    if (c == 0) out[g] = red[0] + b2[0];
}

// ================= launch =================
extern "C" void kernel_launch(void* const* d_in, const int* in_sizes, int n_in,
                              void* d_out, int out_size, void* d_ws, size_t ws_size,
                              hipStream_t stream) {
    const float* x      = (const float*)d_in[0];
    const int*   ei     = (const int*)d_in[1];
    const int*   batch  = (const int*)d_in[2];
    const float* W_emb  = (const float*)d_in[3];
    const float* b_emb  = (const float*)d_in[4];
    const float* W_conv = (const float*)d_in[5];
    const float* b_conv = (const float*)d_in[6];
    const float* gamma  = (const float*)d_in[7];
    const float* beta   = (const float*)d_in[8];
    const float* W1     = (const float*)d_in[9];
    const float* b1     = (const float*)d_in[10];
    const float* g2     = (const float*)d_in[11];
    const float* bt2    = (const float*)d_in[12];
    const float* W2     = (const float*)d_in[13];
    const float* b2     = (const float*)d_in[14];
    float* out = (float*)d_out;

    const int* src = ei;
    const int* dst = ei + NE;

    float* ws = (float*)d_ws;
    float*   h          = ws;                              // NN*HID f32
    ushort4* hwh        = (ushort4*)(h + (size_t)NN * HID); // NN*HID fp16 (NN*64 ushort4)
    float*   hw_end     = (float*)(hwh + (size_t)NN * 64);
    float*   dinv       = hw_end;                          // NN
    float*   stats      = dinv + NN;                       // 1024
    float*   bpart      = stats + 1024;                    // NPART*512
    int*     cnt        = (int*)(bpart + NPART * 512);     // NN
    int*     row_ptr    = cnt + NN;                        // NN+1
    int*     cursor     = row_ptr + NN + 1;                // NN
    int*     bsum       = cursor + NN;                     // 256
    int*     bofs       = bsum + 256;                      // 256
    int*     src_sorted = bofs + 256;                      // NE
    float*   w_sorted   = (float*)(src_sorted + NE);       // NE
    float* pooled = (float*)(src_sorted);                  // aliases CSR (dead by pool)
    float* counts = w_sorted;                              // aliases
    float* ssum  = stats;
    float* ssq   = stats + 256;
    float* scale = stats + 512;
    float* shift = stats + 768;
    float* z     = (float*)hwh;                            // fp32 z after last agg

    const int B = 256;
    const int SB = (NN + 255) / 256;   // 196

    // ---- CSR build ----
    hipMemsetAsync(cnt, 0, NN * sizeof(int), stream);
    hist_dst<<<(NE + B - 1) / B, B, 0, stream>>>(dst, cnt);
    scan_bsum<<<SB, B, 0, stream>>>(cnt, bsum);
    scan_offsets<<<1, B, 0, stream>>>(bsum, bofs, row_ptr);
    scan_emit<<<SB, B, 0, stream>>>(cnt, bofs, row_ptr, cursor, dinv);
    csr_fill<<<(NE + B - 1) / B, B, 0, stream>>>(src, dst, dinv, cursor,
                                                 src_sorted, w_sorted);

    // ---- embedding (fp32 out) ----
    gemm_bias_n256<IN_CH, false><<<(NN + 31) / 32, B, 0, stream>>>(
        x, W_emb, b_emb, nullptr, nullptr, h, nullptr, NN);

    // ---- conv layers ----
    for (int l = 0; l < 3; l++) {
        const float* Wl = W_conv + (size_t)l * HID * HID;
        const float* bl = b_conv + (size_t)l * HID;
        // hwh = f(h) @ Wl  (fp16 out); f = BN affine + relu (identity for l==0)
        gemm_bias_n256<HID, true><<<(NN + 31) / 32, B, 0, stream>>>(
            h, Wl, nullptr,
            (l == 0) ? nullptr : scale, (l == 0) ? nullptr : shift,
            nullptr, (ushort4*)hwh, NN);
        hipMemsetAsync(bpart, 0, NPART * 512 * sizeof(float), stream);
        gcn_aggregate<<<NN / 4, B, 0, stream>>>(hwh, row_ptr, src_sorted, w_sorted,
                                                bl, h, bpart);
        bn_finalize_part<<<1, B, 0, stream>>>(bpart, gamma + l * HID, beta + l * HID,
                                              scale, shift, 1.0f / NN);
    }

    // ---- pool (BN3 affine + relu fused) ----
    hipMemsetAsync(pooled, 0, (size_t)NG * HID * sizeof(float), stream);
    pool_sum<<<(NN + 63) / 64, B, 0, stream>>>(h, batch, scale, shift, pooled);
    graph_counts<<<(NG + B - 1) / B, B, 0, stream>>>(batch, counts);
    pool_div<<<(NG * HID + B - 1) / B, B, 0, stream>>>(pooled, counts);

    // ---- readout ----
    gemm_bias_n256<HID, false><<<(NG + 31) / 32, B, 0, stream>>>(
        pooled, W1, b1, nullptr, nullptr, z, nullptr, NG);
    hipMemsetAsync(stats, 0, 512 * sizeof(float), stream);
    bn_stats<<<64, B, 0, stream>>>(z, ssum, ssq, NG);
    bn_finalize<<<1, B, 0, stream>>>(ssum, ssq, g2, bt2, scale, shift, 1.0f / NG);
    final_out<<<NG, B, 0, stream>>>(z, scale, shift, W2, b2, out);
}

// Round 5
// 585.122 us; speedup vs baseline: 2.7844x; 1.4337x over previous
//
#include <hip/hip_runtime.h>
#include <hip/hip_fp16.h>

#define NN 50000
#define NE 800000
#define IN_CH 128
#define HID 256
#define NG 1024
#define BN_EPS 1e-5f
#define NPART 64

using half8  = __attribute__((ext_vector_type(8))) _Float16;
using floatx4 = __attribute__((ext_vector_type(4))) float;

static __device__ inline unsigned short f2h(float f) {
    _Float16 h = (_Float16)f;   // RNE
    return *reinterpret_cast<unsigned short*>(&h);
}
static __device__ inline float h2f(unsigned short u) {
    _Float16 h = *reinterpret_cast<_Float16*>(&u);
    return (float)h;
}

// ================= CSR build =================
__global__ void hist_dst(const int* __restrict__ dst, int* __restrict__ cnt) {
    int e = blockIdx.x * blockDim.x + threadIdx.x;
    if (e < NE) atomicAdd(&cnt[dst[e]], 1);
}

__global__ void scan_bsum(const int* __restrict__ cnt, int* __restrict__ bsum) {
    __shared__ int red[256];
    int t = threadIdx.x;
    int i = blockIdx.x * 256 + t;
    red[t] = (i < NN) ? cnt[i] : 0;
    __syncthreads();
    for (int s = 128; s > 0; s >>= 1) {
        if (t < s) red[t] += red[t + s];
        __syncthreads();
    }
    if (t == 0) bsum[blockIdx.x] = red[0];
}

__global__ void scan_offsets(const int* __restrict__ bsum, int* __restrict__ bofs,
                             int* __restrict__ row_ptr) {
    __shared__ int sh[256];
    int t = threadIdx.x;
    sh[t] = (t < 196) ? bsum[t] : 0;
    __syncthreads();
    for (int off = 1; off < 256; off <<= 1) {
        int v = (t >= off) ? sh[t - off] : 0;
        __syncthreads();
        sh[t] += v;
        __syncthreads();
    }
    if (t < 196) bofs[t] = (t == 0) ? 0 : sh[t - 1];
    if (t == 0) row_ptr[NN] = NE;
}

__global__ void scan_emit(const int* __restrict__ cnt, const int* __restrict__ bofs,
                          int* __restrict__ row_ptr, int* __restrict__ cursor,
                          float* __restrict__ dinv) {
    __shared__ int sh[256];
    int t = threadIdx.x;
    int i = blockIdx.x * 256 + t;
    int ci = (i < NN) ? cnt[i] : 0;
    sh[t] = ci;
    __syncthreads();
    for (int off = 1; off < 256; off <<= 1) {
        int v = (t >= off) ? sh[t - off] : 0;
        __syncthreads();
        sh[t] += v;
        __syncthreads();
    }
    if (i < NN) {
        int run = bofs[blockIdx.x] + sh[t] - ci;
        row_ptr[i] = run;
        cursor[i] = run;
        dinv[i] = rsqrtf(1.0f + (float)ci);
    }
}

__global__ void csr_fill(const int* __restrict__ src, const int* __restrict__ dst,
                         const float* __restrict__ dinv, int* __restrict__ cursor,
                         int* __restrict__ src_sorted, float* __restrict__ w_sorted) {
    int e = blockIdx.x * blockDim.x + threadIdx.x;
    if (e >= NE) return;
    int s = src[e], d = dst[e];
    int pos = atomicAdd(&cursor[d], 1);
    src_sorted[pos] = s;
    w_sorted[pos] = dinv[s] * dinv[d];
}

// ================= weight reorder: W[K][256] fp32 -> fp16 B-fragment order =====
// Wf[((kc*16 + nt)*64 + lane)*8 + j] = W[kc*32 + (lane>>4)*8 + j][nt*16 + (lane&15)]
__global__ void reorder_w(const float* __restrict__ W, unsigned short* __restrict__ Wf,
                          int K) {
    int idx = blockIdx.x * blockDim.x + threadIdx.x;
    if (idx >= K * 256) return;
    int j    = idx & 7;
    int lane = (idx >> 3) & 63;
    int nt   = (idx >> 9) & 15;
    int kc   = idx >> 13;
    int k = kc * 32 + ((lane >> 4) << 3) + j;
    int n = nt * 16 + (lane & 15);
    Wf[idx] = f2h(W[k * 256 + n]);
}

// ================= MFMA GEMM: C[M,256] = f(A)[M,K] @ W[K,256] (+bias) ==========
// f = relu(a*scale[k]+shift[k]) if a_scale else identity. HOUT: fp16 out else fp32.
// block 256 thr = 4 waves; block tile 64(M)x256(N); wave w -> cols [64w,64w+64)
template <int K, bool HOUT>
__global__ void gemm_mfma(const float* __restrict__ A,
                          const unsigned short* __restrict__ Wf,
                          const float* __restrict__ bias,
                          const float* __restrict__ a_scale,
                          const float* __restrict__ a_shift,
                          float* __restrict__ Cf,
                          unsigned short* __restrict__ Ch, int M) {
    __shared__ _Float16 As[64][40];   // +8 pad: <=2-way banking (free)
    const int tid  = threadIdx.x;
    const int lane = tid & 63;
    const int wv   = tid >> 6;
    const int quad = lane >> 4;
    const int l16  = lane & 15;
    const int m0   = blockIdx.x * 64;

    floatx4 acc[4][4] = {};

    for (int kc = 0; kc < K / 32; kc++) {
        // ---- stage A tile 64x32 (affine+relu fused, fp32->fp16) ----
        {
            int r  = tid >> 2;
            int c8 = (tid & 3) * 8;
            int row = m0 + r;
            float v[8];
            if (row < M) {
                float4 p0 = *(const float4*)&A[(size_t)row * K + kc * 32 + c8];
                float4 p1 = *(const float4*)&A[(size_t)row * K + kc * 32 + c8 + 4];
                v[0] = p0.x; v[1] = p0.y; v[2] = p0.z; v[3] = p0.w;
                v[4] = p1.x; v[5] = p1.y; v[6] = p1.z; v[7] = p1.w;
            } else {
#pragma unroll
                for (int i = 0; i < 8; i++) v[i] = 0.f;
            }
            if (a_scale) {
#pragma unroll
                for (int i = 0; i < 8; i++) {
                    int k = kc * 32 + c8 + i;
                    v[i] = fmaxf(v[i] * a_scale[k] + a_shift[k], 0.f);
                }
            }
#pragma unroll
            for (int i = 0; i < 8; i++) As[r][c8 + i] = (_Float16)v[i];
        }
        __syncthreads();

        half8 af[4], bf[4];
#pragma unroll
        for (int mt = 0; mt < 4; mt++)
            af[mt] = *(const half8*)&As[mt * 16 + l16][quad * 8];
#pragma unroll
        for (int nt = 0; nt < 4; nt++) {
            int ntg = wv * 4 + nt;
            bf[nt] = *(const half8*)&Wf[(size_t)((kc * 16 + ntg) * 64 + lane) * 8];
        }
#pragma unroll
        for (int mt = 0; mt < 4; mt++)
#pragma unroll
            for (int nt = 0; nt < 4; nt++)
                acc[mt][nt] = __builtin_amdgcn_mfma_f32_16x16x32_f16(
                    af[mt], bf[nt], acc[mt][nt], 0, 0, 0);
        __syncthreads();
    }

    // ---- epilogue: C/D layout col=lane&15, row=quad*4+reg ----
#pragma unroll
    for (int mt = 0; mt < 4; mt++) {
#pragma unroll
        for (int nt = 0; nt < 4; nt++) {
            int col = wv * 64 + nt * 16 + l16;
            float bb = bias ? bias[col] : 0.f;
#pragma unroll
            for (int i = 0; i < 4; i++) {
                int row = m0 + mt * 16 + quad * 4 + i;
                if (row < M) {
                    float o = acc[mt][nt][i] + bb;
                    if (HOUT) Ch[(size_t)row * 256 + col] = f2h(o);
                    else      Cf[(size_t)row * 256 + col] = o;
                }
            }
        }
    }
}

// ================= aggregation (fp16 gathers, fused BN-stats to partials) ====
__global__ void gcn_aggregate(const ushort4* __restrict__ hwh,
                              const int* __restrict__ row_ptr,
                              const int* __restrict__ src_sorted,
                              const float* __restrict__ w_sorted,
                              const float* __restrict__ bias,
                              float* __restrict__ outh,
                              float* __restrict__ bpart) {
    const int wv   = threadIdx.x >> 6;
    const int lane = threadIdx.x & 63;
    const int d    = blockIdx.x * 4 + wv;
    const int c0   = lane * 4;

    const int e0 = row_ptr[d];
    const int e1 = row_ptr[d + 1];
    const float sl = 1.0f / (1.0f + (float)(e1 - e0));

    float4 b = *(const float4*)&bias[c0];
    ushort4 vr = hwh[d * 64 + lane];
    float4 acc;
    acc.x = h2f(vr.x) * sl + b.x;
    acc.y = h2f(vr.y) * sl + b.y;
    acc.z = h2f(vr.z) * sl + b.z;
    acc.w = h2f(vr.w) * sl + b.w;

    int e = e0;
    for (; e + 4 <= e1; e += 4) {
        int   s0 = src_sorted[e],     s1 = src_sorted[e + 1];
        int   s2 = src_sorted[e + 2], s3 = src_sorted[e + 3];
        float w0 = w_sorted[e],       w1 = w_sorted[e + 1];
        float w2 = w_sorted[e + 2],   w3 = w_sorted[e + 3];
        ushort4 a0 = hwh[s0 * 64 + lane];
        ushort4 a1 = hwh[s1 * 64 + lane];
        ushort4 a2 = hwh[s2 * 64 + lane];
        ushort4 a3 = hwh[s3 * 64 + lane];
        acc.x += h2f(a0.x) * w0 + h2f(a1.x) * w1 + h2f(a2.x) * w2 + h2f(a3.x) * w3;
        acc.y += h2f(a0.y) * w0 + h2f(a1.y) * w1 + h2f(a2.y) * w2 + h2f(a3.y) * w3;
        acc.z += h2f(a0.z) * w0 + h2f(a1.z) * w1 + h2f(a2.z) * w2 + h2f(a3.z) * w3;
        acc.w += h2f(a0.w) * w0 + h2f(a1.w) * w1 + h2f(a2.w) * w2 + h2f(a3.w) * w3;
    }
    for (; e < e1; e++) {
        int   s0 = src_sorted[e];
        float w0 = w_sorted[e];
        ushort4 a0 = hwh[s0 * 64 + lane];
        acc.x += h2f(a0.x) * w0;
        acc.y += h2f(a0.y) * w0;
        acc.z += h2f(a0.z) * w0;
        acc.w += h2f(a0.w) * w0;
    }
    *(float4*)&outh[d * HID + c0] = acc;

    __shared__ float ls[4][256];
    __shared__ float lq[4][256];
    *(float4*)&ls[wv][c0] = acc;
    float4 q;
    q.x = acc.x * acc.x; q.y = acc.y * acc.y;
    q.z = acc.z * acc.z; q.w = acc.w * acc.w;
    *(float4*)&lq[wv][c0] = q;
    __syncthreads();
    int c = threadIdx.x;
    float s  = ls[0][c] + ls[1][c] + ls[2][c] + ls[3][c];
    float qq = lq[0][c] + lq[1][c] + lq[2][c] + lq[3][c];
    float* pb = bpart + (blockIdx.x & (NPART - 1)) * 512;
    atomicAdd(&pb[c], s);
    atomicAdd(&pb[256 + c], qq);
}

__global__ void bn_finalize_part(const float* __restrict__ bpart,
                                 const float* __restrict__ gamma,
                                 const float* __restrict__ beta,
                                 float* __restrict__ scale, float* __restrict__ shift,
                                 float invM) {
    int c = threadIdx.x;
    float s = 0.f, q = 0.f;
    for (int p = 0; p < NPART; p++) {
        s += bpart[p * 512 + c];
        q += bpart[p * 512 + 256 + c];
    }
    float mu = s * invM;
    float var = q * invM - mu * mu;
    float inv = rsqrtf(var + BN_EPS);
    float sc = inv * gamma[c];
    scale[c] = sc;
    shift[c] = beta[c] - mu * sc;
}

// ================= fp32 VALU GEMM (readout only, M=1024) =================
__global__ void gemm_f32_small(const float* __restrict__ A, const float* __restrict__ W,
                               const float* __restrict__ bias, float* __restrict__ C,
                               int M) {
    __shared__ float As[32][32];
    const int tid  = threadIdx.x;
    const int lane = tid & 63;
    const int wv   = tid >> 6;
    const int c0   = lane * 4;
    const int r0   = wv * 8;
    const int m0   = blockIdx.x * 32;

    float acc[8][4];
#pragma unroll
    for (int m = 0; m < 8; m++)
#pragma unroll
        for (int j = 0; j < 4; j++) acc[m][j] = 0.f;

    for (int kc = 0; kc < HID; kc += 32) {
        __syncthreads();
#pragma unroll
        for (int i = 0; i < 4; i++) {
            int elem = tid + i * 256;
            int r = elem >> 5, kk = elem & 31;
            int row = m0 + r;
            As[r][kk] = (row < M) ? A[row * HID + kc + kk] : 0.f;
        }
        __syncthreads();
#pragma unroll
        for (int kk = 0; kk < 32; kk++) {
            const float4 w4 = *(const float4*)&W[(kc + kk) * 256 + c0];
#pragma unroll
            for (int m = 0; m < 8; m++) {
                float a = As[r0 + m][kk];
                acc[m][0] += a * w4.x;
                acc[m][1] += a * w4.y;
                acc[m][2] += a * w4.z;
                acc[m][3] += a * w4.w;
            }
        }
    }
    float4 bb = *(const float4*)&bias[c0];
#pragma unroll
    for (int m = 0; m < 8; m++) {
        int row = m0 + r0 + m;
        if (row < M) {
            float4 o;
            o.x = acc[m][0] + bb.x;
            o.y = acc[m][1] + bb.y;
            o.z = acc[m][2] + bb.z;
            o.w = acc[m][3] + bb.w;
            *(float4*)&C[row * 256 + c0] = o;
        }
    }
}

// ================= readout BN / pooling / head =================
__global__ void bn_stats(const float* __restrict__ h, float* __restrict__ sum,
                         float* __restrict__ sumsq, int M) {
    int c = threadIdx.x;
    float s = 0.f, q = 0.f;
    for (int r = blockIdx.x; r < M; r += gridDim.x) {
        float v = h[r * HID + c];
        s += v;
        q += v * v;
    }
    atomicAdd(&sum[c], s);
    atomicAdd(&sumsq[c], q);
}

__global__ void bn_finalize(const float* __restrict__ sum,
                            const float* __restrict__ sumsq,
                            const float* __restrict__ gamma,
                            const float* __restrict__ beta,
                            float* __restrict__ scale, float* __restrict__ shift,
                            float invM) {
    int c = threadIdx.x;
    float mu = sum[c] * invM;
    float var = sumsq[c] * invM - mu * mu;
    float inv = rsqrtf(var + BN_EPS);
    float sc = inv * gamma[c];
    scale[c] = sc;
    shift[c] = beta[c] - mu * sc;
}

__global__ void pool_sum(const float* __restrict__ h, const int* __restrict__ batch,
                         const float* __restrict__ scale, const float* __restrict__ shift,
                         float* __restrict__ pooled) {
    int c = threadIdx.x;
    int i0 = blockIdx.x * 64;
    int i1 = (i0 + 64 < NN) ? i0 + 64 : NN;
    float sc = scale[c], sh = shift[c];
    float acc = 0.f;
    int g = batch[i0];
    for (int i = i0; i < i1; i++) {
        int gi = batch[i];
        if (gi != g) {
            atomicAdd(&pooled[g * HID + c], acc);
            acc = 0.f;
            g = gi;
        }
        acc += fmaxf(h[i * HID + c] * sc + sh, 0.f);
    }
    atomicAdd(&pooled[g * HID + c], acc);
}

__global__ void graph_counts(const int* __restrict__ batch, float* __restrict__ counts) {
    int g = blockIdx.x * blockDim.x + threadIdx.x;
    if (g >= NG) return;
    int lo = 0, hi = NN;
    while (lo < hi) { int m = (lo + hi) >> 1; if (batch[m] <= g) lo = m + 1; else hi = m; }
    int ub1 = lo;
    lo = 0; hi = NN;
    int gm = g - 1;
    while (lo < hi) { int m = (lo + hi) >> 1; if (batch[m] <= gm) lo = m + 1; else hi = m; }
    counts[g] = (float)(ub1 - lo);
}

__global__ void pool_div(float* __restrict__ pooled, const float* __restrict__ counts) {
    int idx = blockIdx.x * blockDim.x + threadIdx.x;
    if (idx >= NG * HID) return;
    int g = idx >> 8;
    pooled[idx] /= fmaxf(counts[g], 1.0f);
}

__global__ void final_out(const float* __restrict__ z, const float* __restrict__ scale,
                          const float* __restrict__ shift, const float* __restrict__ W2,
                          const float* __restrict__ b2, float* __restrict__ out) {
    int g = blockIdx.x;
    int c = threadIdx.x;
    float v = z[g * HID + c] * scale[c] + shift[c];
    v = fmaxf(v, 0.f) * W2[c];
    __shared__ float red[256];
    red[c] = v;
    __syncthreads();
    for (int s = 128; s > 0; s >>= 1) {
        if (c < s) red[c] += red[c + s];
        __syncthreads();
    }
    if (c == 0) out[g] = red[0] + b2[0];
}

// ================= launch =================
extern "C" void kernel_launch(void* const* d_in, const int* in_sizes, int n_in,
                              void* d_out, int out_size, void* d_ws, size_t ws_size,
                              hipStream_t stream) {
    const float* x      = (const float*)d_in[0];
    const int*   ei     = (const int*)d_in[1];
    const int*   batch  = (const int*)d_in[2];
    const float* W_emb  = (const float*)d_in[3];
    const float* b_emb  = (const float*)d_in[4];
    const float* W_conv = (const float*)d_in[5];
    const float* b_conv = (const float*)d_in[6];
    const float* gamma  = (const float*)d_in[7];
    const float* beta   = (const float*)d_in[8];
    const float* W1     = (const float*)d_in[9];
    const float* b1     = (const float*)d_in[10];
    const float* g2     = (const float*)d_in[11];
    const float* bt2    = (const float*)d_in[12];
    const float* W2     = (const float*)d_in[13];
    const float* b2     = (const float*)d_in[14];
    float* out = (float*)d_out;

    const int* src = ei;
    const int* dst = ei + NE;

    float* ws = (float*)d_ws;
    float*   h          = ws;                               // NN*HID f32
    ushort4* hwh        = (ushort4*)(h + (size_t)NN * HID); // NN*HID fp16
    float*   hw_end     = (float*)(hwh + (size_t)NN * 64);
    float*   dinv       = hw_end;                           // NN
    float*   stats      = dinv + NN;                        // 1024
    float*   bpart      = stats + 1024;                     // NPART*512
    int*     cnt        = (int*)(bpart + NPART * 512);      // NN
    int*     row_ptr    = cnt + NN;                         // NN+1
    int*     cursor     = row_ptr + NN + 1;                 // NN
    int*     bsum       = cursor + NN;                      // 256
    int*     bofs       = bsum + 256;                       // 256
    unsigned short* wf_emb  = (unsigned short*)(bofs + 256);  // 128*256
    unsigned short* wf_conv = wf_emb + IN_CH * 256;           // 3*256*256
    int*     src_sorted = (int*)(wf_conv + 3 * HID * 256);  // NE
    float*   w_sorted   = (float*)(src_sorted + NE);        // NE
    float* pooled = (float*)(src_sorted);                   // aliases CSR (dead by pool)
    float* counts = w_sorted;                               // aliases
    float* ssum  = stats;
    float* ssq   = stats + 256;
    float* scale = stats + 512;
    float* shift = stats + 768;
    float* z     = (float*)hwh;

    const int B = 256;
    const int SB = (NN + 255) / 256;
    const int GB = (NN + 63) / 64;   // 782 MFMA gemm blocks

    // ---- CSR build ----
    hipMemsetAsync(cnt, 0, NN * sizeof(int), stream);
    hist_dst<<<(NE + B - 1) / B, B, 0, stream>>>(dst, cnt);
    scan_bsum<<<SB, B, 0, stream>>>(cnt, bsum);
    scan_offsets<<<1, B, 0, stream>>>(bsum, bofs, row_ptr);
    scan_emit<<<SB, B, 0, stream>>>(cnt, bofs, row_ptr, cursor, dinv);
    csr_fill<<<(NE + B - 1) / B, B, 0, stream>>>(src, dst, dinv, cursor,
                                                 src_sorted, w_sorted);

    // ---- weight reorder to fp16 fragment layout ----
    reorder_w<<<(IN_CH * 256 + B - 1) / B, B, 0, stream>>>(W_emb, wf_emb, IN_CH);
    for (int l = 0; l < 3; l++)
        reorder_w<<<(HID * 256 + B - 1) / B, B, 0, stream>>>(
            W_conv + (size_t)l * HID * HID, wf_conv + (size_t)l * HID * 256, HID);

    // ---- embedding: h = x @ W_emb + b_emb (fp32 out) ----
    gemm_mfma<IN_CH, false><<<GB, B, 0, stream>>>(
        x, wf_emb, b_emb, nullptr, nullptr, h, nullptr, NN);

    // ---- conv layers ----
    for (int l = 0; l < 3; l++) {
        const float* bl = b_conv + (size_t)l * HID;
        gemm_mfma<HID, true><<<GB, B, 0, stream>>>(
            h, wf_conv + (size_t)l * HID * 256, nullptr,
            (l == 0) ? nullptr : scale, (l == 0) ? nullptr : shift,
            nullptr, (unsigned short*)hwh, NN);
        hipMemsetAsync(bpart, 0, NPART * 512 * sizeof(float), stream);
        gcn_aggregate<<<NN / 4, B, 0, stream>>>(hwh, row_ptr, src_sorted, w_sorted,
                                                bl, h, bpart);
        bn_finalize_part<<<1, B, 0, stream>>>(bpart, gamma + l * HID, beta + l * HID,
                                              scale, shift, 1.0f / NN);
    }

    // ---- pool (BN3 affine + relu fused) ----
    hipMemsetAsync(pooled, 0, (size_t)NG * HID * sizeof(float), stream);
    pool_sum<<<(NN + 63) / 64, B, 0, stream>>>(h, batch, scale, shift, pooled);
    graph_counts<<<(NG + B - 1) / B, B, 0, stream>>>(batch, counts);
    pool_div<<<(NG * HID + B - 1) / B, B, 0, stream>>>(pooled, counts);

    // ---- readout ----
    gemm_f32_small<<<(NG + 31) / 32, B, 0, stream>>>(pooled, W1, b1, z, NG);
    hipMemsetAsync(stats, 0, 512 * sizeof(float), stream);
    bn_stats<<<64, B, 0, stream>>>(z, ssum, ssq, NG);
    bn_finalize<<<1, B, 0, stream>>>(ssum, ssq, g2, bt2, scale, shift, 1.0f / NG);
    final_out<<<NG, B, 0, stream>>>(z, scale, shift, W2, b2, out);
}